// Round 1
// baseline (250.326 us; speedup 1.0000x reference)
//
#include <hip/hip_runtime.h>
#include <hip/hip_bf16.h>
#include <cmath>
#include <cstdint>

// MultiHeadAttention_76338748719257 — MI355X (gfx950) bf16 MFMA implementation.
//
// Pipeline:
//   1) convert fp32 inputs -> bf16 (ws)
//   2) Qp/Kp/Vp = x @ W^T + b   (bf16 NT GEMM, 128x128 tile, BK=64, XOR-swizzled LDS)
//   3) per-head flash attention on contiguous [2048,64] slices (the reference's
//      "faithful reshape" makes head h the contiguous chunk (b*16+h)*2048*64)
//   4) out = O @ wo^T + bo (fp32 output)

typedef __bf16 bf16_t;
typedef bf16_t bf16x8 __attribute__((ext_vector_type(8)));
typedef bf16_t bf16x4 __attribute__((ext_vector_type(4)));
typedef float  f32x4  __attribute__((ext_vector_type(4)));

#define MFMA_16x16x32(a, b, c) __builtin_amdgcn_mfma_f32_16x16x32_bf16((a), (b), (c), 0, 0, 0)

#define GLOAD_LDS16(gptr, lptr)                                                      \
  __builtin_amdgcn_global_load_lds(                                                  \
      (const __attribute__((address_space(1))) void*)(gptr),                         \
      (__attribute__((address_space(3))) void*)(lptr), 16, 0, 0)

namespace {
constexpr int kB = 2, kH = 16, kS = 2048, kE = 1024, kD = 64;
constexpr int kM = kB * kS;             // 4096 GEMM rows
constexpr float kScale = 0.03125f;      // 1/sqrt(E) = 1/32 (reference uses E, not D)
}

// ---------------- fp32 -> bf16 convert (vectorized, grid-stride) ----------------
__global__ void cvt_f32_to_bf16(const float* __restrict__ src,
                                bf16_t* __restrict__ dst, int n4) {
  int stride = gridDim.x * blockDim.x;
  for (int i = blockIdx.x * blockDim.x + threadIdx.x; i < n4; i += stride) {
    float4 v = reinterpret_cast<const float4*>(src)[i];
    bf16x4 o;
    o[0] = (bf16_t)v.x; o[1] = (bf16_t)v.y; o[2] = (bf16_t)v.z; o[3] = (bf16_t)v.w;
    reinterpret_cast<bf16x4*>(dst)[i] = o;
  }
}

// ---------------- NT GEMM: C[M][N] = A[M][K] * Bm[N][K]^T + bias ----------------
// m97-style: 128x128 tile, BK=64, global_load_lds width=16, XOR-swizzled LDS
// (swizzle applied on the SOURCE address so the linear-dest global_load_lds
//  lands data swizzled; reads apply the same involution — rule #21).
template <bool OUTF32>
__global__ __launch_bounds__(256, 2)
void gemm_bt(const bf16_t* __restrict__ A, const bf16_t* __restrict__ Bm,
             const float* __restrict__ bias, void* __restrict__ Cout,
             int M, int N, int K) {
  constexpr int BK = 64;
  __shared__ __align__(16) bf16_t As[128 * BK];
  __shared__ __align__(16) bf16_t Bs[128 * BK];
  const int tid = threadIdx.x, lane = tid & 63, wave = tid >> 6;
  const int fr = lane & 15, fg = lane >> 4;
  const int bm = blockIdx.y * 128, bn = blockIdx.x * 128;
  const int wr = (wave >> 1) * 64, wc = (wave & 1) * 64;
  f32x4 acc[4][4] = {};
  for (int k0 = 0; k0 < K; k0 += BK) {
#pragma unroll
    for (int c = 0; c < 4; ++c) {  // A tile: 128 rows x 64 bf16 = 16KB
      int lin = c * 256 + tid;
      int row = lin >> 3, ch = lin & 7;
      int sch = ch ^ (row & 7);
      GLOAD_LDS16(A + (size_t)(bm + row) * K + k0 + sch * 8, (char*)As + lin * 16);
    }
#pragma unroll
    for (int c = 0; c < 4; ++c) {  // B tile
      int lin = c * 256 + tid;
      int row = lin >> 3, ch = lin & 7;
      int sch = ch ^ (row & 7);
      GLOAD_LDS16(Bm + (size_t)(bn + row) * K + k0 + sch * 8, (char*)Bs + lin * 16);
    }
    __syncthreads();
#pragma unroll
    for (int kk = 0; kk < 2; ++kk) {
      bf16x8 af[4], bfv[4];
#pragma unroll
      for (int i = 0; i < 4; ++i) {
        int row = wr + i * 16 + fr;
        int ch = (kk * 4 + fg) ^ (row & 7);
        af[i] = *reinterpret_cast<const bf16x8*>((const char*)As + row * 128 + ch * 16);
      }
#pragma unroll
      for (int j = 0; j < 4; ++j) {
        int row = wc + j * 16 + fr;
        int ch = (kk * 4 + fg) ^ (row & 7);
        bfv[j] = *reinterpret_cast<const bf16x8*>((const char*)Bs + row * 128 + ch * 16);
      }
#pragma unroll
      for (int i = 0; i < 4; ++i)
#pragma unroll
        for (int j = 0; j < 4; ++j)
          acc[i][j] = MFMA_16x16x32(af[i], bfv[j], acc[i][j]);
    }
    __syncthreads();
  }
  // epilogue: C/D layout row=(lane>>4)*4+r (M side), col=lane&15 (N side)
#pragma unroll
  for (int i = 0; i < 4; ++i) {
#pragma unroll
    for (int j = 0; j < 4; ++j) {
      int col = bn + wc + j * 16 + fr;
      float bv = bias[col];
#pragma unroll
      for (int r = 0; r < 4; ++r) {
        int row = bm + wr + i * 16 + fg * 4 + r;
        float vv = acc[i][j][r] + bv;
        if (OUTF32) reinterpret_cast<float*>(Cout)[(size_t)row * N + col] = vv;
        else        reinterpret_cast<bf16_t*>(Cout)[(size_t)row * N + col] = (bf16_t)vv;
      }
    }
  }
}

// ---------------- flash attention over one [2048,64] head slice ----------------
// grid = (S/128, B*H); 4 waves/block, wave owns 32 q-rows; KV tiles of 64 rows.
__global__ __launch_bounds__(256, 2)
void attn_fwd(const bf16_t* __restrict__ Qp, const bf16_t* __restrict__ Kp,
              const bf16_t* __restrict__ Vp, bf16_t* __restrict__ Op) {
  __shared__ __align__(16) bf16_t Ks[64 * 64];       // K tile, XOR-swizzled rows
  __shared__ __align__(16) bf16_t Vt[64 * 64];       // V^T tile, XOR-swizzled rows
  __shared__ __align__(16) bf16_t Ps[4 * 32 * 64];   // per-wave P tiles
  const int tid = threadIdx.x, lane = tid & 63, wave = tid >> 6;
  const int fr = lane & 15, fg = lane >> 4;
  const size_t base = (size_t)blockIdx.y * kS * kD;
  const int q0 = blockIdx.x * 128 + wave * 32;
  char* const PsW = (char*)Ps + wave * 4096;

  // Q fragments held in registers for the whole kernel (8 loads of 16B)
  bf16x8 aq[2][2];
#pragma unroll
  for (int m = 0; m < 2; ++m)
#pragma unroll
    for (int kk = 0; kk < 2; ++kk)
      aq[m][kk] = *reinterpret_cast<const bf16x8*>(
          Qp + base + (size_t)(q0 + m * 16 + fr) * kD + kk * 32 + fg * 8);

  float Mr[2][4], Lr[2][4];
  f32x4 Oa[2][4] = {};
#pragma unroll
  for (int m = 0; m < 2; ++m)
#pragma unroll
    for (int i = 0; i < 4; ++i) { Mr[m][i] = -__builtin_huge_valf(); Lr[m][i] = 0.f; }

  for (int kt = 0; kt < kS / 64; ++kt) {
    const bf16_t* Kt = Kp + base + (size_t)kt * 64 * kD;
    const bf16_t* Vg = Vp + base + (size_t)kt * 64 * kD;
    // stage K tile via global_load_lds with pre-swizzled source
#pragma unroll
    for (int c = 0; c < 2; ++c) {
      int lin = c * 256 + tid;
      int row = lin >> 3, ch = lin & 7, sch = ch ^ (row & 7);
      GLOAD_LDS16(Kt + row * 64 + sch * 8, (char*)Ks + lin * 16);
    }
    // stage V transposed (reg-staged; swizzled byte addresses)
#pragma unroll
    for (int c = 0; c < 2; ++c) {
      int lin = c * 256 + tid;
      int row = lin >> 3, ch = lin & 7;
      bf16x8 vv = *reinterpret_cast<const bf16x8*>(Vg + row * 64 + ch * 8);
#pragma unroll
      for (int j = 0; j < 8; ++j) {
        int d = ch * 8 + j;                       // d&7 == j
        int byte = (d * 128 + row * 2) ^ (j << 4);
        *reinterpret_cast<bf16_t*>((char*)Vt + byte) = vv[j];
      }
    }
    __syncthreads();

    // scores: S-tile 32q x 64k per wave
    f32x4 sa[2][4] = {};
#pragma unroll
    for (int kk = 0; kk < 2; ++kk) {
      bf16x8 kf[4];
#pragma unroll
      for (int n = 0; n < 4; ++n) {
        int row = n * 16 + fr;
        int ch = (kk * 4 + fg) ^ (row & 7);
        kf[n] = *reinterpret_cast<const bf16x8*>((const char*)Ks + row * 128 + ch * 16);
      }
#pragma unroll
      for (int m = 0; m < 2; ++m)
#pragma unroll
        for (int n = 0; n < 4; ++n)
          sa[m][n] = MFMA_16x16x32(aq[m][kk], kf[n], sa[m][n]);
    }

    // online softmax; P -> LDS (bf16, swizzled)
#pragma unroll
    for (int m = 0; m < 2; ++m) {
#pragma unroll
      for (int i = 0; i < 4; ++i) {
        float s0 = sa[m][0][i] * kScale, s1 = sa[m][1][i] * kScale,
              s2 = sa[m][2][i] * kScale, s3 = sa[m][3][i] * kScale;
        float mx = fmaxf(fmaxf(s0, s1), fmaxf(s2, s3));
#pragma unroll
        for (int msk = 1; msk < 16; msk <<= 1) mx = fmaxf(mx, __shfl_xor(mx, msk));
        float mnew = fmaxf(Mr[m][i], mx);
        float resc = __expf(Mr[m][i] - mnew);   // first tile: exp(-inf)=0
        Mr[m][i] = mnew;
        float p0 = __expf(s0 - mnew), p1 = __expf(s1 - mnew),
              p2 = __expf(s2 - mnew), p3 = __expf(s3 - mnew);
        float rs = (p0 + p1) + (p2 + p3);
#pragma unroll
        for (int msk = 1; msk < 16; msk <<= 1) rs += __shfl_xor(rs, msk);
        Lr[m][i] = Lr[m][i] * resc + rs;
#pragma unroll
        for (int n = 0; n < 4; ++n) Oa[m][n][i] *= resc;
        int prow = m * 16 + fg * 4 + i;
        int rb = prow * 128, sw = (prow & 7) << 4;
        *reinterpret_cast<bf16_t*>(PsW + ((rb + (fr +  0) * 2) ^ sw)) = (bf16_t)p0;
        *reinterpret_cast<bf16_t*>(PsW + ((rb + (fr + 16) * 2) ^ sw)) = (bf16_t)p1;
        *reinterpret_cast<bf16_t*>(PsW + ((rb + (fr + 32) * 2) ^ sw)) = (bf16_t)p2;
        *reinterpret_cast<bf16_t*>(PsW + ((rb + (fr + 48) * 2) ^ sw)) = (bf16_t)p3;
      }
    }
    asm volatile("s_waitcnt lgkmcnt(0)" ::: "memory");  // P writes -> P reads (same wave)

    // PV: O += P * V  (A = P rows, B = Vt rows)
#pragma unroll
    for (int ks = 0; ks < 2; ++ks) {
      bf16x8 pf[2], vf[4];
#pragma unroll
      for (int m = 0; m < 2; ++m) {
        int prow = m * 16 + fr;
        int ch = (ks * 4 + fg) ^ (prow & 7);
        pf[m] = *reinterpret_cast<const bf16x8*>(PsW + prow * 128 + ch * 16);
      }
#pragma unroll
      for (int n = 0; n < 4; ++n) {
        int drow = n * 16 + fr;
        int ch = (ks * 4 + fg) ^ (drow & 7);
        vf[n] = *reinterpret_cast<const bf16x8*>((const char*)Vt + drow * 128 + ch * 16);
      }
#pragma unroll
      for (int m = 0; m < 2; ++m)
#pragma unroll
        for (int n = 0; n < 4; ++n)
          Oa[m][n] = MFMA_16x16x32(pf[m], vf[n], Oa[m][n]);
    }
    __syncthreads();  // protect Ks/Vt before next tile's staging
  }

  // epilogue: O /= L, store bf16 into the contiguous [2048,64] head slice
#pragma unroll
  for (int m = 0; m < 2; ++m)
#pragma unroll
    for (int i = 0; i < 4; ++i) {
      float inv = 1.0f / Lr[m][i];
      int row = q0 + m * 16 + fg * 4 + i;
#pragma unroll
      for (int n = 0; n < 4; ++n)
        Op[base + (size_t)row * kD + n * 16 + fr] = (bf16_t)(Oa[m][n][i] * inv);
    }
}

// ---------------- host launch ----------------
extern "C" void kernel_launch(void* const* d_in, const int* in_sizes, int n_in,
                              void* d_out, int out_size, void* d_ws, size_t ws_size,
                              hipStream_t stream) {
  (void)in_sizes; (void)n_in; (void)out_size; (void)ws_size;
  const float* q  = (const float*)d_in[0];
  const float* k  = (const float*)d_in[1];
  const float* v  = (const float*)d_in[2];
  const float* wq = (const float*)d_in[3];
  const float* bq = (const float*)d_in[4];
  const float* wk = (const float*)d_in[5];
  const float* bk = (const float*)d_in[6];
  const float* wv = (const float*)d_in[7];
  const float* bv = (const float*)d_in[8];
  const float* wo = (const float*)d_in[9];
  const float* bo = (const float*)d_in[10];
  float* out = (float*)d_out;

  char* ws = (char*)d_ws;
  const size_t MB = 1ull << 20;
  bf16_t* qb  = (bf16_t*)(ws +  0 * MB);   // [4096,1024] bf16 inputs
  bf16_t* kb  = (bf16_t*)(ws +  8 * MB);
  bf16_t* vb  = (bf16_t*)(ws + 16 * MB);
  bf16_t* wqb = (bf16_t*)(ws + 24 * MB);   // [1024,1024] bf16 weights
  bf16_t* wkb = (bf16_t*)(ws + 26 * MB);
  bf16_t* wvb = (bf16_t*)(ws + 28 * MB);
  bf16_t* wob = (bf16_t*)(ws + 30 * MB);
  bf16_t* Qp  = (bf16_t*)(ws + 32 * MB);   // projected Q/K/V (bf16)
  bf16_t* Kp  = (bf16_t*)(ws + 40 * MB);
  bf16_t* Vp  = (bf16_t*)(ws + 48 * MB);
  bf16_t* Opb = (bf16_t*)(ws + 56 * MB);   // attention output (bf16)

  const int nQKV4 = (kM * kE) / 4;  // 1,048,576 float4 groups
  const int nW4   = (kE * kE) / 4;  // 262,144
  cvt_f32_to_bf16<<<dim3(512), dim3(256), 0, stream>>>(q,  qb,  nQKV4);
  cvt_f32_to_bf16<<<dim3(512), dim3(256), 0, stream>>>(k,  kb,  nQKV4);
  cvt_f32_to_bf16<<<dim3(512), dim3(256), 0, stream>>>(v,  vb,  nQKV4);
  cvt_f32_to_bf16<<<dim3(256), dim3(256), 0, stream>>>(wq, wqb, nW4);
  cvt_f32_to_bf16<<<dim3(256), dim3(256), 0, stream>>>(wk, wkb, nW4);
  cvt_f32_to_bf16<<<dim3(256), dim3(256), 0, stream>>>(wv, wvb, nW4);
  cvt_f32_to_bf16<<<dim3(256), dim3(256), 0, stream>>>(wo, wob, nW4);

  dim3 pg(kE / 128, kM / 128);  // (8, 32)
  gemm_bt<false><<<pg, 256, 0, stream>>>(qb, wqb, bq, Qp, kM, kE, kE);
  gemm_bt<false><<<pg, 256, 0, stream>>>(kb, wkb, bk, Kp, kM, kE, kE);
  gemm_bt<false><<<pg, 256, 0, stream>>>(vb, wvb, bv, Vp, kM, kE, kE);

  attn_fwd<<<dim3(kS / 128, kB * kH), 256, 0, stream>>>(Qp, Kp, Vp, Opb);

  gemm_bt<true><<<pg, 256, 0, stream>>>(Opb, wob, bo, out, kM, kE, kE);
}

// Round 2
// 216.481 us; speedup vs baseline: 1.1563x; 1.1563x over previous
//
#include <hip/hip_runtime.h>
#include <hip/hip_bf16.h>
#include <cstdint>

// MultiHeadAttention_76338748719257 — MI355X (gfx950) bf16 MFMA implementation. R2.
//
// Pipeline:
//   1) convert fp32 inputs -> bf16 (batched convert kernels)
//   2) Qp/Kp/Vp = x @ W^T + b (bf16 NT GEMM, 128x128 tile, BK=64, XOR-swizzled LDS).
//      Q projection additionally scaled by 1/sqrt(E) (folded out of the softmax).
//   3) per-head V transpose (Vp [2048,64] -> VpT [64,2048]) — done ONCE per element
//      instead of per q-block inside attention.
//   4) flash attention: QBLK=64 (grid 1024 = 4 blocks/CU), KBLK=128, K and V^T staged
//      via global_load_lds with pre-swizzled source, P per-wave in LDS reused across
//      the two 64-k PV halves. XCD-swizzled block mapping (4 heads per XCD).
//   5) out = O @ wo^T + bo (fp32 output)

typedef __bf16 bf16_t;
typedef bf16_t bf16x8 __attribute__((ext_vector_type(8)));
typedef bf16_t bf16x4 __attribute__((ext_vector_type(4)));
typedef float  f32x4  __attribute__((ext_vector_type(4)));

#define MFMA_16x16x32(a, b, c) __builtin_amdgcn_mfma_f32_16x16x32_bf16((a), (b), (c), 0, 0, 0)

#define GLOAD_LDS16(gptr, lptr)                                                      \
  __builtin_amdgcn_global_load_lds(                                                  \
      (const __attribute__((address_space(1))) void*)(gptr),                         \
      (__attribute__((address_space(3))) void*)(lptr), 16, 0, 0)

namespace {
constexpr int kB = 2, kH = 16, kS = 2048, kE = 1024, kD = 64;
constexpr int kM = kB * kS;              // 4096 GEMM rows
constexpr float kQScale = 0.03125f;      // 1/sqrt(E) = 1/32, folded into Q projection
}

// ---------------- fp32 -> bf16 convert (up to 4 buffers per launch) ----------------
__global__ void cvt_batch(const float* __restrict__ s0, const float* __restrict__ s1,
                          const float* __restrict__ s2, const float* __restrict__ s3,
                          bf16_t* __restrict__ d0, bf16_t* __restrict__ d1,
                          bf16_t* __restrict__ d2, bf16_t* __restrict__ d3, int n4) {
  const float* s; bf16_t* d;
  switch (blockIdx.y) {
    case 0:  s = s0; d = d0; break;
    case 1:  s = s1; d = d1; break;
    case 2:  s = s2; d = d2; break;
    default: s = s3; d = d3; break;
  }
  int stride = gridDim.x * blockDim.x;
  for (int i = blockIdx.x * blockDim.x + threadIdx.x; i < n4; i += stride) {
    float4 v = reinterpret_cast<const float4*>(s)[i];
    bf16x4 o;
    o[0] = (bf16_t)v.x; o[1] = (bf16_t)v.y; o[2] = (bf16_t)v.z; o[3] = (bf16_t)v.w;
    reinterpret_cast<bf16x4*>(d)[i] = o;
  }
}

// ---------------- NT GEMM: C[M][N] = (A[M][K] * Bm[N][K]^T + bias) * scale ----------
template <bool OUTF32>
__global__ __launch_bounds__(256, 2)
void gemm_bt(const bf16_t* __restrict__ A, const bf16_t* __restrict__ Bm,
             const float* __restrict__ bias, void* __restrict__ Cout,
             int M, int N, int K, float scale) {
  constexpr int BK = 64;
  __shared__ __align__(16) bf16_t As[128 * BK];
  __shared__ __align__(16) bf16_t Bs[128 * BK];
  const int tid = threadIdx.x, lane = tid & 63, wave = tid >> 6;
  const int fr = lane & 15, fg = lane >> 4;
  const int bm = blockIdx.y * 128, bn = blockIdx.x * 128;
  const int wr = (wave >> 1) * 64, wc = (wave & 1) * 64;
  f32x4 acc[4][4] = {};
  for (int k0 = 0; k0 < K; k0 += BK) {
#pragma unroll
    for (int c = 0; c < 4; ++c) {
      int lin = c * 256 + tid;
      int row = lin >> 3, ch = lin & 7;
      int sch = ch ^ (row & 7);
      GLOAD_LDS16(A + (size_t)(bm + row) * K + k0 + sch * 8, (char*)As + lin * 16);
    }
#pragma unroll
    for (int c = 0; c < 4; ++c) {
      int lin = c * 256 + tid;
      int row = lin >> 3, ch = lin & 7;
      int sch = ch ^ (row & 7);
      GLOAD_LDS16(Bm + (size_t)(bn + row) * K + k0 + sch * 8, (char*)Bs + lin * 16);
    }
    __syncthreads();
#pragma unroll
    for (int kk = 0; kk < 2; ++kk) {
      bf16x8 af[4], bfv[4];
#pragma unroll
      for (int i = 0; i < 4; ++i) {
        int row = wr + i * 16 + fr;
        int ch = (kk * 4 + fg) ^ (row & 7);
        af[i] = *reinterpret_cast<const bf16x8*>((const char*)As + row * 128 + ch * 16);
      }
#pragma unroll
      for (int j = 0; j < 4; ++j) {
        int row = wc + j * 16 + fr;
        int ch = (kk * 4 + fg) ^ (row & 7);
        bfv[j] = *reinterpret_cast<const bf16x8*>((const char*)Bs + row * 128 + ch * 16);
      }
#pragma unroll
      for (int i = 0; i < 4; ++i)
#pragma unroll
        for (int j = 0; j < 4; ++j)
          acc[i][j] = MFMA_16x16x32(af[i], bfv[j], acc[i][j]);
    }
    __syncthreads();
  }
#pragma unroll
  for (int i = 0; i < 4; ++i) {
#pragma unroll
    for (int j = 0; j < 4; ++j) {
      int col = bn + wc + j * 16 + fr;
      float bv = bias[col];
#pragma unroll
      for (int r = 0; r < 4; ++r) {
        int row = bm + wr + i * 16 + fg * 4 + r;
        float vv = (acc[i][j][r] + bv) * scale;
        if (OUTF32) reinterpret_cast<float*>(Cout)[(size_t)row * N + col] = vv;
        else        reinterpret_cast<bf16_t*>(Cout)[(size_t)row * N + col] = (bf16_t)vv;
      }
    }
  }
}

// ---------------- per-head V transpose: Vp [head][2048][64] -> VpT [head][64][2048] --
__global__ __launch_bounds__(256)
void vtranspose(const bf16_t* __restrict__ Vp, bf16_t* __restrict__ VpT) {
  __shared__ __align__(16) bf16_t T[256 * 64];  // 32 KB, XOR-swizzled
  const int tid = threadIdx.x;
  const size_t hb = (size_t)blockIdx.y * (kS * kD);
  const bf16_t* src = Vp + hb + (size_t)blockIdx.x * 256 * kD;
  bf16_t* dst = VpT + hb + blockIdx.x * 256;
#pragma unroll
  for (int c = 0; c < 8; ++c) {
    int lin = c * 256 + tid;
    int row = lin >> 3, ch = lin & 7;
    bf16x8 v = *reinterpret_cast<const bf16x8*>(src + row * kD + ch * 8);
    *reinterpret_cast<bf16x8*>((char*)T + row * 128 + ((ch ^ ((row >> 3) & 7)) * 16)) = v;
  }
  __syncthreads();
#pragma unroll
  for (int c = 0; c < 8; ++c) {
    int lin = c * 256 + tid;
    int d = lin >> 5, kc = lin & 31;
    bf16x8 o;
#pragma unroll
    for (int e = 0; e < 8; ++e) {
      int s = kc * 8 + e;
      o[e] = *reinterpret_cast<const bf16_t*>(
          (const char*)T + s * 128 + (((d >> 3) ^ ((s >> 3) & 7)) * 16) + (d & 7) * 2);
    }
    *reinterpret_cast<bf16x8*>(dst + (size_t)d * kS + kc * 8) = o;
  }
}

// ---------------- flash attention ----------------
// grid = 1024 blocks (32 heads x 32 q-tiles of 64), 4 waves, wave owns 16 q rows.
// KBLK=128. K staged [128][64] (swizzled), V^T staged [64][128] (swizzled),
// P per-wave [16][64] reused across the two 64-k PV halves.
__global__ __launch_bounds__(256, 4)
void attn_fwd(const bf16_t* __restrict__ Qp, const bf16_t* __restrict__ Kp,
              const bf16_t* __restrict__ VpT, bf16_t* __restrict__ Op) {
  __shared__ __align__(16) bf16_t Ks[128 * 64];      // 16 KB
  __shared__ __align__(16) bf16_t Vs[64 * 128];      // 16 KB
  __shared__ __align__(16) bf16_t Ps[4 * 16 * 64];   //  8 KB
  const int tid = threadIdx.x, lane = tid & 63, wave = tid >> 6;
  const int fr = lane & 15, fg = lane >> 4;
  // XCD swizzle: 1024 blocks, 8 XCDs -> each XCD gets 128 consecutive (4 whole heads)
  const int bid = blockIdx.x;
  const int newb = (bid & 7) * 128 + (bid >> 3);
  const int head = newb >> 5;
  const int qt = newb & 31;
  const size_t hbase = (size_t)head * (kS * kD);
  const int q0 = qt * 64 + wave * 16;
  char* const PsW = (char*)Ps + wave * 2048;

  bf16x8 aq[2];
#pragma unroll
  for (int kk = 0; kk < 2; ++kk)
    aq[kk] = *reinterpret_cast<const bf16x8*>(
        Qp + hbase + (size_t)(q0 + fr) * kD + kk * 32 + fg * 8);

  float Mr[4], Lr[4];
  f32x4 Oa[4] = {};
#pragma unroll
  for (int i = 0; i < 4; ++i) { Mr[i] = -3.0e38f; Lr[i] = 0.f; }

  for (int kt = 0; kt < kS / 128; ++kt) {
    const bf16_t* Kt = Kp + hbase + (size_t)kt * 128 * kD;
    const bf16_t* Vt = VpT + hbase + kt * 128;
#pragma unroll
    for (int c = 0; c < 4; ++c) {  // K tile [128][64], row=128B, chunk^= (row&7)
      int lin = c * 256 + tid;
      int row = lin >> 3, ch = lin & 7, sch = ch ^ (row & 7);
      GLOAD_LDS16(Kt + row * 64 + sch * 8, (char*)Ks + lin * 16);
    }
#pragma unroll
    for (int c = 0; c < 4; ++c) {  // V^T tile [64][128], row=256B, chunk^= (row&15)
      int lin = c * 256 + tid;
      int row = lin >> 4, ch = lin & 15, sch = ch ^ (row & 15);
      GLOAD_LDS16(Vt + (size_t)row * kS + sch * 8, (char*)Vs + lin * 16);
    }
    __syncthreads();

    // ---- QK^T: S[16q][128k] per wave ----
    f32x4 sa[8] = {};
#pragma unroll
    for (int kk = 0; kk < 2; ++kk) {
      bf16x8 kf[8];
#pragma unroll
      for (int n = 0; n < 8; ++n) {
        int row = n * 16 + fr;
        int ch = (kk * 4 + fg) ^ (row & 7);
        kf[n] = *reinterpret_cast<const bf16x8*>((const char*)Ks + row * 128 + ch * 16);
      }
#pragma unroll
      for (int n = 0; n < 8; ++n) sa[n] = MFMA_16x16x32(aq[kk], kf[n], sa[n]);
    }

    // ---- softmax part 1: full-row max, rescale, exp(half A: k 0..63), write P ----
#pragma unroll
    for (int i = 0; i < 4; ++i) {
      float mx = fmaxf(fmaxf(fmaxf(sa[0][i], sa[1][i]), fmaxf(sa[2][i], sa[3][i])),
                       fmaxf(fmaxf(sa[4][i], sa[5][i]), fmaxf(sa[6][i], sa[7][i])));
#pragma unroll
      for (int m = 1; m < 16; m <<= 1) mx = fmaxf(mx, __shfl_xor(mx, m));
      float mnew = fmaxf(Mr[i], mx);
      float resc = __expf(Mr[i] - mnew);
      Mr[i] = mnew;
      float p0 = __expf(sa[0][i] - mnew), p1 = __expf(sa[1][i] - mnew),
            p2 = __expf(sa[2][i] - mnew), p3 = __expf(sa[3][i] - mnew);
      float rs = (p0 + p1) + (p2 + p3);
#pragma unroll
      for (int m = 1; m < 16; m <<= 1) rs += __shfl_xor(rs, m);
      Lr[i] = Lr[i] * resc + rs;
#pragma unroll
      for (int n = 0; n < 4; ++n) Oa[n][i] *= resc;
      int q = fg * 4 + i;
      int rb = q * 128, sw = (q & 7) << 4;
      *reinterpret_cast<bf16_t*>(PsW + ((rb + (fr +  0) * 2) ^ sw)) = (bf16_t)p0;
      *reinterpret_cast<bf16_t*>(PsW + ((rb + (fr + 16) * 2) ^ sw)) = (bf16_t)p1;
      *reinterpret_cast<bf16_t*>(PsW + ((rb + (fr + 32) * 2) ^ sw)) = (bf16_t)p2;
      *reinterpret_cast<bf16_t*>(PsW + ((rb + (fr + 48) * 2) ^ sw)) = (bf16_t)p3;
    }
    asm volatile("s_waitcnt lgkmcnt(0)" ::: "memory");
    __builtin_amdgcn_sched_barrier(0);

    // ---- PV half A (k 0..63) ----
#pragma unroll
    for (int ks = 0; ks < 2; ++ks) {
      bf16x8 pf, vf[4];
      {
        int ch = (ks * 4 + fg) ^ (fr & 7);
        pf = *reinterpret_cast<const bf16x8*>(PsW + fr * 128 + ch * 16);
      }
#pragma unroll
      for (int n = 0; n < 4; ++n) {
        int row = n * 16 + fr;
        int ch = (ks * 4 + fg) ^ (row & 15);
        vf[n] = *reinterpret_cast<const bf16x8*>((const char*)Vs + row * 256 + ch * 16);
      }
#pragma unroll
      for (int n = 0; n < 4; ++n) Oa[n] = MFMA_16x16x32(pf, vf[n], Oa[n]);
    }
    asm volatile("s_waitcnt lgkmcnt(0)" ::: "memory");
    __builtin_amdgcn_sched_barrier(0);

    // ---- softmax part 2: exp(half B: k 64..127), overwrite P ----
#pragma unroll
    for (int i = 0; i < 4; ++i) {
      float p0 = __expf(sa[4][i] - Mr[i]), p1 = __expf(sa[5][i] - Mr[i]),
            p2 = __expf(sa[6][i] - Mr[i]), p3 = __expf(sa[7][i] - Mr[i]);
      float rs = (p0 + p1) + (p2 + p3);
#pragma unroll
      for (int m = 1; m < 16; m <<= 1) rs += __shfl_xor(rs, m);
      Lr[i] += rs;
      int q = fg * 4 + i;
      int rb = q * 128, sw = (q & 7) << 4;
      *reinterpret_cast<bf16_t*>(PsW + ((rb + (fr +  0) * 2) ^ sw)) = (bf16_t)p0;
      *reinterpret_cast<bf16_t*>(PsW + ((rb + (fr + 16) * 2) ^ sw)) = (bf16_t)p1;
      *reinterpret_cast<bf16_t*>(PsW + ((rb + (fr + 32) * 2) ^ sw)) = (bf16_t)p2;
      *reinterpret_cast<bf16_t*>(PsW + ((rb + (fr + 48) * 2) ^ sw)) = (bf16_t)p3;
    }
    asm volatile("s_waitcnt lgkmcnt(0)" ::: "memory");
    __builtin_amdgcn_sched_barrier(0);

    // ---- PV half B (k 64..127) ----
#pragma unroll
    for (int ks = 2; ks < 4; ++ks) {
      bf16x8 pf, vf[4];
      {
        int ch = ((ks & 1) * 4 + fg) ^ (fr & 7);
        pf = *reinterpret_cast<const bf16x8*>(PsW + fr * 128 + ch * 16);
      }
#pragma unroll
      for (int n = 0; n < 4; ++n) {
        int row = n * 16 + fr;
        int ch = (ks * 4 + fg) ^ (row & 15);
        vf[n] = *reinterpret_cast<const bf16x8*>((const char*)Vs + row * 256 + ch * 16);
      }
#pragma unroll
      for (int n = 0; n < 4; ++n) Oa[n] = MFMA_16x16x32(pf, vf[n], Oa[n]);
    }
    __syncthreads();
  }

  // epilogue: O /= L
#pragma unroll
  for (int i = 0; i < 4; ++i) {
    float inv = 1.0f / Lr[i];
    int row = q0 + fg * 4 + i;
#pragma unroll
    for (int n = 0; n < 4; ++n)
      Op[hbase + (size_t)row * kD + n * 16 + fr] = (bf16_t)(Oa[n][i] * inv);
  }
}

// ---------------- host launch ----------------
extern "C" void kernel_launch(void* const* d_in, const int* in_sizes, int n_in,
                              void* d_out, int out_size, void* d_ws, size_t ws_size,
                              hipStream_t stream) {
  (void)in_sizes; (void)n_in; (void)out_size; (void)ws_size;
  const float* q  = (const float*)d_in[0];
  const float* k  = (const float*)d_in[1];
  const float* v  = (const float*)d_in[2];
  const float* wq = (const float*)d_in[3];
  const float* bq = (const float*)d_in[4];
  const float* wk = (const float*)d_in[5];
  const float* bk = (const float*)d_in[6];
  const float* wv = (const float*)d_in[7];
  const float* bv = (const float*)d_in[8];
  const float* wo = (const float*)d_in[9];
  const float* bo = (const float*)d_in[10];
  float* out = (float*)d_out;

  char* ws = (char*)d_ws;
  const size_t MB = 1ull << 20;
  bf16_t* qb  = (bf16_t*)(ws +  0 * MB);   // [4096,1024] bf16 inputs
  bf16_t* kb  = (bf16_t*)(ws +  8 * MB);
  bf16_t* vb  = (bf16_t*)(ws + 16 * MB);
  bf16_t* wqb = (bf16_t*)(ws + 24 * MB);   // [1024,1024] bf16 weights
  bf16_t* wkb = (bf16_t*)(ws + 26 * MB);
  bf16_t* wvb = (bf16_t*)(ws + 28 * MB);
  bf16_t* wob = (bf16_t*)(ws + 30 * MB);
  bf16_t* Qp  = (bf16_t*)(ws + 32 * MB);   // projected Q/K/V (bf16)
  bf16_t* Kp  = (bf16_t*)(ws + 40 * MB);
  bf16_t* Vp  = (bf16_t*)(ws + 48 * MB);
  bf16_t* Opb = (bf16_t*)(ws + 56 * MB);   // attention output (bf16)
  bf16_t* VpT = (bf16_t*)(ws +  0 * MB);   // reuses qb (dead after Q projection)

  const int nQKV4 = (kM * kE) / 4;
  const int nW4   = (kE * kE) / 4;
  cvt_batch<<<dim3(512, 3), 256, 0, stream>>>(q, k, v, v, qb, kb, vb, vb, nQKV4);
  cvt_batch<<<dim3(128, 4), 256, 0, stream>>>(wq, wk, wv, wo, wqb, wkb, wvb, wob, nW4);

  dim3 pg(kE / 128, kM / 128);  // (8, 32)
  gemm_bt<false><<<pg, 256, 0, stream>>>(qb, wqb, bq, Qp, kM, kE, kE, kQScale);
  gemm_bt<false><<<pg, 256, 0, stream>>>(kb, wkb, bk, Kp, kM, kE, kE, 1.0f);
  gemm_bt<false><<<pg, 256, 0, stream>>>(vb, wvb, bv, Vp, kM, kE, kE, 1.0f);

  vtranspose<<<dim3(kS / 256, kB * kH), 256, 0, stream>>>(Vp, VpT);

  attn_fwd<<<dim3(1024), 256, 0, stream>>>(Qp, Kp, VpT, Opb);

  gemm_bt<true><<<pg, 256, 0, stream>>>(Opb, wob, bo, out, kM, kE, kE, 1.0f);
}

// Round 3
// 128.053 us; speedup vs baseline: 1.9549x; 1.6906x over previous
//
#include <hip/hip_runtime.h>
#include <hip/hip_bf16.h>
#include <cstdint>

// MultiHeadAttention_76338748719257 — MI355X (gfx950). R3.
// attn: swapped-operand 32x32 MFMA flash attention (m214 structure):
//   S^T = mfma(K,Q) -> lane holds 32 k-values for q=lane&31 -> in-lane softmax,
//   P->bf16 via v_cvt_pk_bf16_f32 + permlane32_swap (P never touches LDS),
//   O^T = mfma(V^T,P) -> per-q normalize lane-local. Double-buffered K/V staging.
// GEMMs: fused QKV projection (one [4096]x[3072] NT GEMM), final GEMM BN=64.

typedef __bf16 bf16_t;
typedef bf16_t bf16x8 __attribute__((ext_vector_type(8)));
typedef bf16_t bf16x4 __attribute__((ext_vector_type(4)));
typedef float  f32x4  __attribute__((ext_vector_type(4)));
typedef float  f32x16 __attribute__((ext_vector_type(16)));
typedef unsigned int u32;
typedef u32 u32x2 __attribute__((ext_vector_type(2)));

#define MFMA16(a, b, c) __builtin_amdgcn_mfma_f32_16x16x32_bf16((a), (b), (c), 0, 0, 0)
#define MFMA32(a, b, c) __builtin_amdgcn_mfma_f32_32x32x16_bf16((a), (b), (c), 0, 0, 0)

#define GLOAD_LDS16(gptr, lptr)                                                      \
  __builtin_amdgcn_global_load_lds(                                                  \
      (const __attribute__((address_space(1))) void*)(gptr),                         \
      (__attribute__((address_space(3))) void*)(lptr), 16, 0, 0)

namespace {
constexpr int kS = 2048, kE = 1024, kD = 64;
constexpr int kM = 4096;                 // B*S rows
constexpr float kQScale = 0.03125f;      // 1/sqrt(E), folded into Q projection
constexpr float kL2E = 1.44269504088896f;
}

__device__ inline u32 pkbf(float a, float b) {
  u32 r;
  asm("v_cvt_pk_bf16_f32 %0, %1, %2" : "=v"(r) : "v"(a), "v"(b));
  return r;
}

// Build PV B-fragment ks from 8 consecutive S^T regs (see derivation in R3 notes):
// word0/1 = lower-half-lane group, word2/3 = upper — one permlane32_swap fills two.
__device__ inline bf16x8 make_pfrag(float v0, float v1, float v2, float v3,
                                    float v4, float v5, float v6, float v7) {
  u32 A0 = pkbf(v0, v1), A1 = pkbf(v2, v3);
  u32 B0 = pkbf(v4, v5), B1 = pkbf(v6, v7);
  u32x2 r0 = __builtin_amdgcn_permlane32_swap(A0, B0, false, false);
  u32x2 r1 = __builtin_amdgcn_permlane32_swap(A1, B1, false, false);
  union { u32 w[4]; bf16x8 v; } u;
  u.w[0] = r0[0]; u.w[1] = r1[0]; u.w[2] = r0[1]; u.w[3] = r1[1];
  return u.v;
}

// ---------------- fp32 -> bf16 convert (4 buffers per launch) ----------------
__global__ void cvt_batch(const float* __restrict__ s0, const float* __restrict__ s1,
                          const float* __restrict__ s2, const float* __restrict__ s3,
                          bf16_t* __restrict__ d0, bf16_t* __restrict__ d1,
                          bf16_t* __restrict__ d2, bf16_t* __restrict__ d3, int n4) {
  const float* s; bf16_t* d;
  switch (blockIdx.y) {
    case 0:  s = s0; d = d0; break;
    case 1:  s = s1; d = d1; break;
    case 2:  s = s2; d = d2; break;
    default: s = s3; d = d3; break;
  }
  int stride = gridDim.x * blockDim.x;
  for (int i = blockIdx.x * blockDim.x + threadIdx.x; i < n4; i += stride) {
    float4 v = reinterpret_cast<const float4*>(s)[i];
    bf16x4 o;
    o[0] = (bf16_t)v.x; o[1] = (bf16_t)v.y; o[2] = (bf16_t)v.z; o[3] = (bf16_t)v.w;
    reinterpret_cast<bf16x4*>(d)[i] = o;
  }
}

// ---------------- fused QKV projection GEMM ----------------
// C[4096][3072] = x_sel @ Wqkv^T + bias_sel; col region r=0,1,2 -> (q,k,v) inputs,
// biases, outputs; Q region scaled by 1/32. 128x128 tile, BK=64, grid (24,32).
__global__ __launch_bounds__(256, 2)
void gemm_qkv(const bf16_t* __restrict__ qb, const bf16_t* __restrict__ kb,
              const bf16_t* __restrict__ vb, const bf16_t* __restrict__ W,
              const float* __restrict__ bq, const float* __restrict__ bk,
              const float* __restrict__ bv,
              bf16_t* __restrict__ Qp, bf16_t* __restrict__ Kp, bf16_t* __restrict__ Vp) {
  constexpr int K = kE, BK = 64;
  __shared__ __align__(16) bf16_t As[128 * BK];
  __shared__ __align__(16) bf16_t Bs[128 * BK];
  const int tid = threadIdx.x, lane = tid & 63, wave = tid >> 6;
  const int fr = lane & 15, fg = lane >> 4;
  const int region = blockIdx.x >> 3;              // 0=Q,1=K,2=V (uniform per block)
  const int bm = blockIdx.y * 128, bn = blockIdx.x * 128;
  const int bnl = (blockIdx.x & 7) * 128;          // col within region
  const bf16_t* A = region == 0 ? qb : region == 1 ? kb : vb;
  const float* bias = region == 0 ? bq : region == 1 ? bk : bv;
  bf16_t* Cp = region == 0 ? Qp : region == 1 ? Kp : Vp;
  const float scale = region == 0 ? kQScale : 1.0f;
  const int wr = (wave >> 1) * 64, wc = (wave & 1) * 64;
  f32x4 acc[4][4] = {};
  for (int k0 = 0; k0 < K; k0 += BK) {
#pragma unroll
    for (int c = 0; c < 4; ++c) {
      int lin = c * 256 + tid, row = lin >> 3, ch = lin & 7, sch = ch ^ (row & 7);
      GLOAD_LDS16(A + (size_t)(bm + row) * K + k0 + sch * 8, (char*)As + lin * 16);
    }
#pragma unroll
    for (int c = 0; c < 4; ++c) {
      int lin = c * 256 + tid, row = lin >> 3, ch = lin & 7, sch = ch ^ (row & 7);
      GLOAD_LDS16(W + (size_t)(bn + row) * K + k0 + sch * 8, (char*)Bs + lin * 16);
    }
    __syncthreads();
#pragma unroll
    for (int kk = 0; kk < 2; ++kk) {
      bf16x8 af[4], bfv[4];
#pragma unroll
      for (int i = 0; i < 4; ++i) {
        int row = wr + i * 16 + fr;
        int ch = (kk * 4 + fg) ^ (row & 7);
        af[i] = *reinterpret_cast<const bf16x8*>((const char*)As + row * 128 + ch * 16);
      }
#pragma unroll
      for (int j = 0; j < 4; ++j) {
        int row = wc + j * 16 + fr;
        int ch = (kk * 4 + fg) ^ (row & 7);
        bfv[j] = *reinterpret_cast<const bf16x8*>((const char*)Bs + row * 128 + ch * 16);
      }
#pragma unroll
      for (int i = 0; i < 4; ++i)
#pragma unroll
        for (int j = 0; j < 4; ++j)
          acc[i][j] = MFMA16(af[i], bfv[j], acc[i][j]);
    }
    __syncthreads();
  }
#pragma unroll
  for (int i = 0; i < 4; ++i)
#pragma unroll
    for (int j = 0; j < 4; ++j) {
      int coll = bnl + wc + j * 16 + fr;
      float bvv = bias[coll];
#pragma unroll
      for (int r = 0; r < 4; ++r) {
        int row = bm + wr + i * 16 + fg * 4 + r;
        Cp[(size_t)row * kE + coll] = (bf16_t)((acc[i][j][r] + bvv) * scale);
      }
    }
}

// ---------------- final GEMM: out[4096][1024] f32 = O @ wo^T + bo, BN=64 ----------
__global__ __launch_bounds__(256, 2)
void gemm_out(const bf16_t* __restrict__ A, const bf16_t* __restrict__ Bm,
              const float* __restrict__ bias, float* __restrict__ Cout) {
  constexpr int K = kE, BK = 64;
  __shared__ __align__(16) bf16_t As[128 * BK];
  __shared__ __align__(16) bf16_t Bs[64 * BK];
  const int tid = threadIdx.x, lane = tid & 63, wave = tid >> 6;
  const int fr = lane & 15, fg = lane >> 4;
  const int bm = blockIdx.y * 128, bn = blockIdx.x * 64;
  const int wr = wave * 32;
  f32x4 acc[2][4] = {};
  for (int k0 = 0; k0 < K; k0 += BK) {
#pragma unroll
    for (int c = 0; c < 4; ++c) {
      int lin = c * 256 + tid, row = lin >> 3, ch = lin & 7, sch = ch ^ (row & 7);
      GLOAD_LDS16(A + (size_t)(bm + row) * K + k0 + sch * 8, (char*)As + lin * 16);
    }
#pragma unroll
    for (int c = 0; c < 2; ++c) {
      int lin = c * 256 + tid, row = lin >> 3, ch = lin & 7, sch = ch ^ (row & 7);
      GLOAD_LDS16(Bm + (size_t)(bn + row) * K + k0 + sch * 8, (char*)Bs + lin * 16);
    }
    __syncthreads();
#pragma unroll
    for (int kk = 0; kk < 2; ++kk) {
      bf16x8 af[2], bfv[4];
#pragma unroll
      for (int i = 0; i < 2; ++i) {
        int row = wr + i * 16 + fr;
        int ch = (kk * 4 + fg) ^ (row & 7);
        af[i] = *reinterpret_cast<const bf16x8*>((const char*)As + row * 128 + ch * 16);
      }
#pragma unroll
      for (int j = 0; j < 4; ++j) {
        int row = bn - bn + j * 16 + fr;  // rows 0..63 of Bs
        int ch = (kk * 4 + fg) ^ (row & 7);
        bfv[j] = *reinterpret_cast<const bf16x8*>((const char*)Bs + row * 128 + ch * 16);
      }
#pragma unroll
      for (int i = 0; i < 2; ++i)
#pragma unroll
        for (int j = 0; j < 4; ++j)
          acc[i][j] = MFMA16(af[i], bfv[j], acc[i][j]);
    }
    __syncthreads();
  }
#pragma unroll
  for (int i = 0; i < 2; ++i)
#pragma unroll
    for (int j = 0; j < 4; ++j) {
      int col = bn + j * 16 + fr;
      float bvv = bias[col];
#pragma unroll
      for (int r = 0; r < 4; ++r) {
        int row = bm + wr + i * 16 + fg * 4 + r;
        Cout[(size_t)row * kE + col] = acc[i][j][r] + bvv;
      }
    }
}

// ---------------- per-head V transpose: Vp [head][2048][64] -> VpT [head][64][2048] --
__global__ __launch_bounds__(256)
void vtranspose(const bf16_t* __restrict__ Vp, bf16_t* __restrict__ VpT) {
  __shared__ __align__(16) bf16_t T[256 * 64];
  const int tid = threadIdx.x;
  const size_t hb = (size_t)blockIdx.y * (kS * kD);
  const bf16_t* src = Vp + hb + (size_t)blockIdx.x * 256 * kD;
  bf16_t* dst = VpT + hb + blockIdx.x * 256;
#pragma unroll
  for (int c = 0; c < 8; ++c) {
    int lin = c * 256 + tid;
    int row = lin >> 3, ch = lin & 7;
    bf16x8 v = *reinterpret_cast<const bf16x8*>(src + row * kD + ch * 8);
    *reinterpret_cast<bf16x8*>((char*)T + row * 128 + ((ch ^ ((row >> 3) & 7)) * 16)) = v;
  }
  __syncthreads();
#pragma unroll
  for (int c = 0; c < 8; ++c) {
    int lin = c * 256 + tid;
    int d = lin >> 5, kc = lin & 31;
    bf16x8 o;
#pragma unroll
    for (int e = 0; e < 8; ++e) {
      int s = kc * 8 + e;
      o[e] = *reinterpret_cast<const bf16_t*>(
          (const char*)T + s * 128 + (((d >> 3) ^ ((s >> 3) & 7)) * 16) + (d & 7) * 2);
    }
    *reinterpret_cast<bf16x8*>(dst + (size_t)d * kS + kc * 8) = o;
  }
}

// ---------------- flash attention, swapped-operand 32x32 ----------------
// grid 512 = 32 heads x 16 q-tiles of 128; 4 waves x 32 q-rows; KVBLK=64.
__global__ __launch_bounds__(256, 3)
void attn_fwd(const bf16_t* __restrict__ Qp, const bf16_t* __restrict__ Kp,
              const bf16_t* __restrict__ VpT, bf16_t* __restrict__ Op) {
  __shared__ __align__(16) char smem[32768];  // 2 x (K 8KB + V^T 8KB)
  const int tid = threadIdx.x, lane = tid & 63, wave = tid >> 6;
  const int ql = lane & 31, hi = lane >> 5;
  // XCD swizzle: 64 consecutive blocks (4 heads) per XCD
  const int newb = (blockIdx.x & 7) * 64 + (blockIdx.x >> 3);
  const int head = newb >> 4, qt = newb & 15;
  const size_t hbase = (size_t)head * (kS * kD);
  const int q0 = qt * 128 + wave * 32;

  // Q B-fragments: frag ct holds Q[q0+ql][16ct + 8hi .. +8]
  bf16x8 qf[4];
#pragma unroll
  for (int ct = 0; ct < 4; ++ct)
    qf[ct] = *reinterpret_cast<const bf16x8*>(
        Qp + hbase + (size_t)(q0 + ql) * kD + ct * 16 + hi * 8);

  float m = -3.0e38f, Lp = 0.0f;
  f32x16 o0 = {}, o1 = {};  // O^T acc: rows d (dt=0: 0..31, dt=1: 32..63), col q=ql

  // prologue: stage tile 0 into buf 0
  {
    const bf16_t* Kt = Kp + hbase;
    const bf16_t* Vt = VpT + hbase;
#pragma unroll
    for (int c = 0; c < 2; ++c) {
      int lin = c * 256 + tid, row = lin >> 3, ch = lin & 7, sch = ch ^ (row & 7);
      GLOAD_LDS16(Kt + row * kD + sch * 8, smem + lin * 16);
      GLOAD_LDS16(Vt + (size_t)row * kS + sch * 8, smem + 8192 + lin * 16);
    }
  }

  for (int kt = 0; kt < kS / 64; ++kt) {
    __syncthreads();  // data-ready for buf[kt&1] (drains my gload_lds)
    const int cb = (kt & 1) * 16384;
    if (kt + 1 < kS / 64) {  // stage next tile; in flight during compute
      const int nb = ((kt + 1) & 1) * 16384;
      const bf16_t* Kt = Kp + hbase + (size_t)(kt + 1) * 64 * kD;
      const bf16_t* Vt = VpT + hbase + (kt + 1) * 64;
#pragma unroll
      for (int c = 0; c < 2; ++c) {
        int lin = c * 256 + tid, row = lin >> 3, ch = lin & 7, sch = ch ^ (row & 7);
        GLOAD_LDS16(Kt + row * kD + sch * 8, smem + nb + lin * 16);
        GLOAD_LDS16(Vt + (size_t)row * kS + sch * 8, smem + nb + 8192 + lin * 16);
      }
    }

    // ---- S^T = K . Q^T : lane holds S[k][q=ql], k split by (reg, hi) ----
    f32x16 s0 = {}, s1 = {};
#pragma unroll
    for (int ct = 0; ct < 4; ++ct) {
      bf16x8 k0 = *reinterpret_cast<const bf16x8*>(
          smem + cb + ql * 128 + (((2 * ct + hi) ^ (ql & 7)) * 16));
      bf16x8 k1 = *reinterpret_cast<const bf16x8*>(
          smem + cb + (32 + ql) * 128 + (((2 * ct + hi) ^ (ql & 7)) * 16));
      s0 = MFMA32(k0, qf[ct], s0);
      s1 = MFMA32(k1, qf[ct], s1);
    }

    // ---- in-lane online softmax (32 values for q=ql; scale folded into Q) ----
    float t0 = -3.0e38f, t1 = -3.0e38f, t2 = -3.0e38f, t3 = -3.0e38f;
#pragma unroll
    for (int r = 0; r < 16; r += 4) {
      t0 = fmaxf(t0, fmaxf(s0[r], s0[r + 1])); t1 = fmaxf(t1, fmaxf(s0[r + 2], s0[r + 3]));
      t2 = fmaxf(t2, fmaxf(s1[r], s1[r + 1])); t3 = fmaxf(t3, fmaxf(s1[r + 2], s1[r + 3]));
    }
    float tm = fmaxf(fmaxf(t0, t1), fmaxf(t2, t3));
    tm = fmaxf(tm, __shfl_xor(tm, 32));
    if (!__all(tm <= m + 8.0f)) {  // defer-max: rescale only on real max growth
      float mn = fmaxf(m, tm);
      float rs = __builtin_amdgcn_exp2f((m - mn) * kL2E);
      m = mn; Lp *= rs;
#pragma unroll
      for (int r = 0; r < 16; ++r) { o0[r] *= rs; o1[r] *= rs; }
    }
    const float ml = m * kL2E;
    float a0 = 0.f, a1 = 0.f;
#pragma unroll
    for (int r = 0; r < 16; ++r) {
      s0[r] = __builtin_amdgcn_exp2f(__builtin_fmaf(s0[r], kL2E, -ml));
      s1[r] = __builtin_amdgcn_exp2f(__builtin_fmaf(s1[r], kL2E, -ml));
      a0 += s0[r]; a1 += s1[r];
    }
    Lp += a0 + a1;

    // ---- P -> bf16 PV fragments (in-register, T12) ----
    bf16x8 pf[4];
    pf[0] = make_pfrag(s0[0], s0[1], s0[2], s0[3], s0[4], s0[5], s0[6], s0[7]);
    pf[1] = make_pfrag(s0[8], s0[9], s0[10], s0[11], s0[12], s0[13], s0[14], s0[15]);
    pf[2] = make_pfrag(s1[0], s1[1], s1[2], s1[3], s1[4], s1[5], s1[6], s1[7]);
    pf[3] = make_pfrag(s1[8], s1[9], s1[10], s1[11], s1[12], s1[13], s1[14], s1[15]);

    // ---- O^T += V^T . P^T ----
#pragma unroll
    for (int ks = 0; ks < 4; ++ks) {
      bf16x8 v0 = *reinterpret_cast<const bf16x8*>(
          smem + cb + 8192 + ql * 128 + (((2 * ks + hi) ^ (ql & 7)) * 16));
      bf16x8 v1 = *reinterpret_cast<const bf16x8*>(
          smem + cb + 8192 + (32 + ql) * 128 + (((2 * ks + hi) ^ (ql & 7)) * 16));
      o0 = MFMA32(v0, pf[ks], o0);
      o1 = MFMA32(v1, pf[ks], o1);
    }
  }

  // ---- epilogue: normalize (lane-local, q=ql), transpose via LDS, store ----
  float L = Lp + __shfl_xor(Lp, 32);
  float inv = 1.0f / L;
#pragma unroll
  for (int r = 0; r < 16; ++r) { o0[r] *= inv; o1[r] *= inv; }
  const int wb = wave * 4096;
#pragma unroll
  for (int c = 0; c < 4; ++c) {
    {  // dt = 0
      u32 w0 = pkbf(o0[4 * c + 0], o0[4 * c + 1]);
      u32 w1 = pkbf(o0[4 * c + 2], o0[4 * c + 3]);
      int d0 = 8 * c + 4 * hi;
      int byte = (wb + ql * 128 + d0 * 2) ^ ((ql & 7) << 4);
      *reinterpret_cast<u32x2*>(smem + byte) = (u32x2){w0, w1};
    }
    {  // dt = 1
      u32 w0 = pkbf(o1[4 * c + 0], o1[4 * c + 1]);
      u32 w1 = pkbf(o1[4 * c + 2], o1[4 * c + 3]);
      int d0 = 32 + 8 * c + 4 * hi;
      int byte = (wb + ql * 128 + d0 * 2) ^ ((ql & 7) << 4);
      *reinterpret_cast<u32x2*>(smem + byte) = (u32x2){w0, w1};
    }
  }
  asm volatile("s_waitcnt lgkmcnt(0)" ::: "memory");
  __builtin_amdgcn_sched_barrier(0);
#pragma unroll
  for (int it = 0; it < 4; ++it) {
    int lin = it * 64 + lane;
    int qr = lin >> 3, ch = lin & 7;
    int byte = wb + qr * 128 + ((ch * 16) ^ ((qr & 7) << 4));
    bf16x8 vrow = *reinterpret_cast<const bf16x8*>(smem + byte);
    *reinterpret_cast<bf16x8*>(Op + hbase + (size_t)(q0 + qr) * kD + ch * 8) = vrow;
  }
}

// ---------------- host launch ----------------
extern "C" void kernel_launch(void* const* d_in, const int* in_sizes, int n_in,
                              void* d_out, int out_size, void* d_ws, size_t ws_size,
                              hipStream_t stream) {
  (void)in_sizes; (void)n_in; (void)out_size; (void)ws_size;
  const float* q  = (const float*)d_in[0];
  const float* k  = (const float*)d_in[1];
  const float* v  = (const float*)d_in[2];
  const float* wq = (const float*)d_in[3];
  const float* bq = (const float*)d_in[4];
  const float* wk = (const float*)d_in[5];
  const float* bk = (const float*)d_in[6];
  const float* wv = (const float*)d_in[7];
  const float* bv = (const float*)d_in[8];
  const float* wo = (const float*)d_in[9];
  const float* bo = (const float*)d_in[10];
  float* out = (float*)d_out;

  char* ws = (char*)d_ws;
  const size_t MB = 1ull << 20;
  bf16_t* qb   = (bf16_t*)(ws +  0 * MB);  // [4096,1024] bf16 inputs
  bf16_t* kb   = (bf16_t*)(ws +  8 * MB);
  bf16_t* vb   = (bf16_t*)(ws + 16 * MB);
  bf16_t* wqkv = (bf16_t*)(ws + 24 * MB);  // packed [3][1024][1024] bf16
  bf16_t* wob  = (bf16_t*)(ws + 30 * MB);
  bf16_t* Qp   = (bf16_t*)(ws + 32 * MB);  // projections (bf16), Q pre-scaled
  bf16_t* Kp   = (bf16_t*)(ws + 40 * MB);
  bf16_t* Vp   = (bf16_t*)(ws + 48 * MB);
  bf16_t* Opb  = (bf16_t*)(ws + 56 * MB);  // attention output (bf16)
  bf16_t* VpT  = (bf16_t*)(ws +  0 * MB);  // reuses qb (dead after projection)

  const int nQKV4 = (kM * kE) / 4;
  const int nW4 = (kE * kE) / 4;
  cvt_batch<<<dim3(512, 3), 256, 0, stream>>>(q, k, v, v, qb, kb, vb, vb, nQKV4);
  cvt_batch<<<dim3(128, 4), 256, 0, stream>>>(wq, wk, wv, wo, wqkv, wqkv + 1048576,
                                              wqkv + 2097152, wob, nW4);

  gemm_qkv<<<dim3(24, 32), 256, 0, stream>>>(qb, kb, vb, wqkv, bq, bk, bv, Qp, Kp, Vp);

  vtranspose<<<dim3(kS / 256, 32), 256, 0, stream>>>(Vp, VpT);

  attn_fwd<<<dim3(512), 256, 0, stream>>>(Qp, Kp, VpT, Opb);

  gemm_out<<<dim3(16, 32), 256, 0, stream>>>(Opb, wob, bo, out);
}